// Round 11
// baseline (88.456 us; speedup 1.0000x reference)
//
#include <hip/hip_runtime.h>

// PlaceCellNetwork forward: out = softmax(tanh([x,1] @ Wh^T + bh + prev @ Wf) @ Wo^T + bo)
// B=4M, IN=2, HID=20, OUT=10.
//
// R11: PERSISTENT GRID-STRIDE STREAMING. Evidence: harness fillBuffer hits
// 6.8 TB/s (640MB, 9.8% occupancy) -- a LOOPED write stream; our one-shot
// blocks reach only ~4 TB/s app-level. One-shot waves never overlap their
// own reads/writes and 7813 short blocks pay launch+endpgm-drain constantly.
// This round: 768 resident blocks (3/CU), each loops ~10 tiles with
// double-buffered LDS slabs; prefetch loads for tile t+1 issue BEFORE
// compute of tile t (T14 async-stage split), ds_write lands after; stores
// NT (R8's best). 2 barriers/iter. Compute core = verified R5/R8 (absmax 2e-3).
//
// Algebra folded at repack:
//   a'' = 2*log2e*(Wh x + bh + Wf^T prev);  r = rcp(1+2^a'')
//   l'  = log2e*(bo+rowsum(Wo)) - 2*log2e*Wo . r ;  out = 2^l' / sum(2^l')
//   (|l'| < ~12 -> exp2 cannot overflow -> softmax max-pass dropped)

#define HID 20
#define OUT 10
#define RPB 512                  // rows per tile (256 threads x 2 rows)
#define PSTR 11                  // LDS row stride in words (odd -> conflict-free)
#define SLABW (RPB * PSTR)       // 5632 words per slab

typedef float f32x2 __attribute__((ext_vector_type(2)));
typedef float f32x4 __attribute__((ext_vector_type(4)));

__device__ __forceinline__ float fast_rcp(float x) { return __builtin_amdgcn_rcpf(x); }
__device__ __forceinline__ float fast_exp2(float x) { return __builtin_amdgcn_exp2f(x); }
__device__ __forceinline__ f32x2 sp(float s) { return (f32x2){s, s}; }

#define EACH10(F) F(0) F(1) F(2) F(3) F(4) F(5) F(6) F(7) F(8) F(9)
#define PIN(v) asm volatile("" : "+v"(v))

// ---- weight repack: scalar layout, 24 floats per hidden unit ----
// per-i block at ws[24*i]:
//   [0]=S*Wh[i][0] [1]=S*Wh[i][1] [2]=S*(Wh[i][2]+bh[i]) [3]=pad
//   [4+o]=S*Wf[o][i]   [14+o]=-S*Wo[o][i]
// ws[480+o] = L*(bo[o]+sum_i Wo[o][i]) ;  S=2*log2e, L=log2e
__global__ void repack_kernel(const float* __restrict__ Wh, const float* __restrict__ bh,
                              const float* __restrict__ Wo, const float* __restrict__ bo,
                              const float* __restrict__ Wf, float* __restrict__ ws) {
    const float S = 2.8853900817779268f;  // 2*log2(e)
    const float L = 1.4426950408889634f;  // log2(e)
    int t = threadIdx.x;
    if (t < HID) {
        float* b = ws + 24 * t;
        b[0] = S * Wh[3 * t + 0];
        b[1] = S * Wh[3 * t + 1];
        b[2] = S * (Wh[3 * t + 2] + bh[t]);
        b[3] = 0.0f;
        for (int o = 0; o < OUT; ++o) {
            b[4 + o]  = S * Wf[o * HID + t];
            b[14 + o] = -S * Wo[o * HID + t];
        }
    } else if (t < HID + OUT) {
        int o = t - HID;
        float s = bo[o];
        for (int i = 0; i < HID; ++i) s += Wo[o * HID + i];
        ws[480 + o] = L * s;
    }
}

// ---- main kernel: persistent, double-buffered, prefetch-pipelined ----
__global__ __launch_bounds__(256, 3) void pcn_kernel(
    const float* __restrict__ x, const float* __restrict__ prev,
    const float* __restrict__ w, float* __restrict__ out, long B) {
    __shared__ float lds[2][SLABW];      // 45056 B -> 3 blocks/CU
    const int t = threadIdx.x;
    const long ntile = (B + RPB - 1) / RPB;
    long tile = blockIdx.x;
    if (tile >= ntile) return;
    const long step = gridDim.x;

    // ---- prologue: stage first tile into lds[0] ----
    {
        const long base = tile * RPB;
        const int V = (B - base < RPB) ? (int)(B - base) : RPB;
        const int NF4 = (OUT * V) >> 2;
        const f32x4* src = reinterpret_cast<const f32x4*>(prev + base * OUT);
#pragma unroll
        for (int k = 0; k < 5; ++k) {
            const int idx = t + 256 * k;
            if (idx < NF4) {
                const f32x4 v = src[idx];
                const float vv[4] = {v.x, v.y, v.z, v.w};
                const int f0 = 4 * idx;
#pragma unroll
                for (int j = 0; j < 4; ++j) {
                    const int f = f0 + j;
                    const int r = f / OUT;
                    lds[0][PSTR * r + (f - OUT * r)] = vv[j];
                }
            }
        }
    }
    __syncthreads();

    int cur = 0;
    while (true) {
        const long base = tile * RPB;
        const int V = (B - base < RPB) ? (int)(B - base) : RPB;
        const int NF4 = (OUT * V) >> 2;
        const long nxt = tile + step;
        const bool more = nxt < ntile;

        // ---- 1. issue prefetch loads for tile nxt (no wait) ----
        f32x4 pf0 = {}, pf1 = {}, pf2 = {}, pf3 = {}, pf4 = {};
        bool pv0 = false, pv1 = false, pv2 = false, pv3 = false, pv4 = false;
        if (more) {
            const long nbase = nxt * RPB;
            const int nV = (B - nbase < RPB) ? (int)(B - nbase) : RPB;
            const int nNF4 = (OUT * nV) >> 2;
            const f32x4* src = reinterpret_cast<const f32x4*>(prev + nbase * OUT);
#define PFL(k) { const int idx = t + 256 * k; pv##k = idx < nNF4; \
                 if (pv##k) pf##k = src[idx]; }
            PFL(0) PFL(1) PFL(2) PFL(3) PFL(4)
#undef PFL
        }

        // ---- 2. compute rows (base+t, base+t+256) from lds[cur] ----
        const bool aok = t < V;
        const bool bok = (t + 256) < V;
        const float* ra = lds[cur] + PSTR * t;
        const float* rb = lds[cur] + PSTR * (t + 256);

        f32x2 x0, x1;
        {
            f32x2 xa = {0.0f, 0.0f}, xb = {0.0f, 0.0f};
            if (aok) xa = *reinterpret_cast<const f32x2*>(x + 2 * (base + t));
            if (bok) xb = *reinterpret_cast<const f32x2*>(x + 2 * (base + t + 256));
            x0 = (f32x2){xa.x, xb.x};
            x1 = (f32x2){xa.y, xb.y};
        }
#define DECLP(o) f32x2 p##o = {ra[o], rb[o]}; PIN(p##o);
        EACH10(DECLP)
#undef DECLP

#define INITL(o) f32x2 l##o = sp(w[480 + o]);
        EACH10(INITL)
#undef INITL
#pragma unroll
        for (int i = 0; i < HID; ++i) {
            const float* wb = w + 24 * i;
            f32x2 a = sp(wb[2]);
            a += sp(wb[0]) * x0;
            a += sp(wb[1]) * x1;
#define FB(o) a += sp(wb[4 + o]) * p##o;
            EACH10(FB)
#undef FB
            f32x2 r;
            r.x = fast_rcp(1.0f + fast_exp2(a.x));
            r.y = fast_rcp(1.0f + fast_exp2(a.y));
#define LO(o) l##o += sp(wb[14 + o]) * r;
            EACH10(LO)
#undef LO
        }
#define EX(o) l##o.x = fast_exp2(l##o.x); l##o.y = fast_exp2(l##o.y);
        EACH10(EX)
#undef EX
        const f32x2 s = ((l0 + l1) + (l2 + l3)) + (((l4 + l5) + (l6 + l7)) + (l8 + l9));
        f32x2 rs;
        rs.x = fast_rcp(s.x);
        rs.y = fast_rcp(s.y);
#define SC(o) l##o *= rs;
        EACH10(SC)
#undef SC

        // ---- 3. all compute reads of lds[cur] done ----
        __syncthreads();

        // ---- 4. results -> lds[cur] dense ----
        if (aok) {
            f32x2* d = reinterpret_cast<f32x2*>(lds[cur] + 10 * t);
            d[0] = (f32x2){l0.x, l1.x}; d[1] = (f32x2){l2.x, l3.x};
            d[2] = (f32x2){l4.x, l5.x}; d[3] = (f32x2){l6.x, l7.x};
            d[4] = (f32x2){l8.x, l9.x};
        }
        if (bok) {
            f32x2* d = reinterpret_cast<f32x2*>(lds[cur] + 10 * (t + 256));
            d[0] = (f32x2){l0.y, l1.y}; d[1] = (f32x2){l2.y, l3.y};
            d[2] = (f32x2){l4.y, l5.y}; d[3] = (f32x2){l6.y, l7.y};
            d[4] = (f32x2){l8.y, l9.y};
        }

        // ---- 5. prefetch -> lds[cur^1] (vmcnt wait happens here) ----
        if (more) {
            float* nslab = lds[cur ^ 1];
#define PFW(k) if (pv##k) { \
                const float vv[4] = {pf##k.x, pf##k.y, pf##k.z, pf##k.w}; \
                const int f0 = 4 * (t + 256 * k); \
                _Pragma("unroll") \
                for (int j = 0; j < 4; ++j) { \
                    const int f = f0 + j; \
                    const int r = f / OUT; \
                    nslab[PSTR * r + (f - OUT * r)] = vv[j]; \
                } }
            PFW(0) PFW(1) PFW(2) PFW(3) PFW(4)
#undef PFW
        }

        // ---- 6. results + next-tile inputs visible ----
        __syncthreads();

        // ---- 7. dense NT copy-out of lds[cur] ----
        {
            f32x4* dst = reinterpret_cast<f32x4*>(out + base * OUT);
            const f32x4* sl = reinterpret_cast<const f32x4*>(lds[cur]);
#pragma unroll
            for (int k = 0; k < 5; ++k) {
                const int idx = t + 256 * k;
                if (idx < NF4) __builtin_nontemporal_store(sl[idx], dst + idx);
            }
        }

        if (!more) break;
        tile = nxt;
        cur ^= 1;
    }
}

// ---- fallback (no workspace): 1 row/thread ----
__global__ __launch_bounds__(256) void pcn_fallback(
    const float* __restrict__ x, const float* __restrict__ prev,
    const float* __restrict__ Wh, const float* __restrict__ bh,
    const float* __restrict__ Wo, const float* __restrict__ bo,
    const float* __restrict__ Wf, float* __restrict__ out, long B) {
    const long r = (long)blockIdx.x * blockDim.x + threadIdx.x;
    if (r >= B) return;
    const float x0 = x[2 * r], x1 = x[2 * r + 1];
#define DECLP(o) float p##o = prev[10 * r + o];
    EACH10(DECLP)
#undef DECLP
#define DECLL(o) float l##o = bo[o];
    EACH10(DECLL)
#undef DECLL
#pragma unroll
    for (int i = 0; i < HID; ++i) {
        float a = fmaf(Wh[3 * i], x0, fmaf(Wh[3 * i + 1], x1, Wh[3 * i + 2] + bh[i]));
#define FB(o) a = fmaf(Wf[o * HID + i], p##o, a);
        EACH10(FB)
#undef FB
        const float h = 1.0f - 2.0f * fast_rcp(1.0f + __expf(2.0f * a));
#define LO(o) l##o = fmaf(Wo[o * HID + i], h, l##o);
        EACH10(LO)
#undef LO
    }
    float m = l0;
#define MX(o) m = fmaxf(m, l##o);
    MX(1) MX(2) MX(3) MX(4) MX(5) MX(6) MX(7) MX(8) MX(9)
#undef MX
    float s = 0.0f;
#define EX(o) l##o = __expf(l##o - m); s += l##o;
    EACH10(EX)
#undef EX
    const float rs = fast_rcp(s);
#define ST(o) out[10 * r + o] = l##o * rs;
    EACH10(ST)
#undef ST
}

extern "C" void kernel_launch(void* const* d_in, const int* in_sizes, int n_in,
                              void* d_out, int out_size, void* d_ws, size_t ws_size,
                              hipStream_t stream) {
    const float* x    = (const float*)d_in[0];
    const float* prev = (const float*)d_in[1];
    const float* Wh   = (const float*)d_in[2];
    const float* bh   = (const float*)d_in[3];
    const float* Wo   = (const float*)d_in[4];
    const float* bo   = (const float*)d_in[5];
    const float* Wf   = (const float*)d_in[6];
    float* out = (float*)d_out;

    const long B = in_sizes[0] / 2;

    if (ws_size >= 490 * sizeof(float)) {
        float* ws = (float*)d_ws;
        repack_kernel<<<1, 64, 0, stream>>>(Wh, bh, Wo, bo, Wf, ws);
        const long ntile = (B + RPB - 1) / RPB;
        int grid = 768;                         // 3 blocks/CU x 256 CU, persistent
        if (ntile < grid) grid = (int)ntile;
        pcn_kernel<<<grid, 256, 0, stream>>>(x, prev, ws, out, B);
    } else {
        const int gb = (int)((B + 255) / 256);
        pcn_fallback<<<gb, 256, 0, stream>>>(x, prev, Wh, bh, Wo, bo, Wf, out, B);
    }
}

// Round 12
// 75.968 us; speedup vs baseline: 1.1644x; 1.1644x over previous
//
#include <hip/hip_runtime.h>

// PlaceCellNetwork forward: out = softmax(tanh([x,1] @ Wh^T + bh + prev @ Wf) @ Wo^T + bo)
// B=4M, IN=2, HID=20, OUT=10.
//
// R12: DMA STAGING + MAX OCCUPANCY. Synthesis of R2-R11: kernel is
// read-latency-limited by outstanding-load depth (VGPR-staged loads cap
// in-flight bytes; R11's occupancy drop proved the direction). Changes:
//  - global_load_lds (width 16) stages prev DIRECTLY into LDS: no VGPR
//    round-trip, ~50 VGPR total, loads queue without register pressure.
//    LDS layout = AoS-linear (m104: DMA dest is linear; transpose dropped;
//    4-way bank conflict on compute ds_reads is 1.58x and hidden).
//  - LDS = 20480 B exactly -> 8 blocks/CU, 32 waves/CU (100% occupancy).
//  - x loads hoisted before the barrier (issue with staging loads).
//  - NT stores kept (R8 best). One-shot grid (persistence proved null).
// Compute core unchanged (verified absmax 2e-3 since R3):
//   a'' = 2*log2e*(Wh x + bh + Wf^T prev);  r = rcp(1+2^a'')
//   l'  = log2e*(bo+rowsum(Wo)) - 2*log2e*Wo . r ;  out = 2^l' / sum(2^l')

#define HID 20
#define OUT 10
#define RPB 512                 // rows per block (256 threads x 2 rows)
#define LDSW (RPB * OUT)        // 5120 words = 20480 B

typedef float f32x2 __attribute__((ext_vector_type(2)));
typedef float f32x4 __attribute__((ext_vector_type(4)));
typedef float __attribute__((address_space(1))) as1f;
typedef float __attribute__((address_space(3))) as3f;

__device__ __forceinline__ float fast_rcp(float x) { return __builtin_amdgcn_rcpf(x); }
__device__ __forceinline__ float fast_exp2(float x) { return __builtin_amdgcn_exp2f(x); }
__device__ __forceinline__ f32x2 sp(float s) { return (f32x2){s, s}; }

#define EACH10(F) F(0) F(1) F(2) F(3) F(4) F(5) F(6) F(7) F(8) F(9)
#define PIN(v) asm volatile("" : "+v"(v))

// ---- weight repack: scalar layout, 24 floats per hidden unit ----
// per-i block at ws[24*i]:
//   [0]=S*Wh[i][0] [1]=S*Wh[i][1] [2]=S*(Wh[i][2]+bh[i]) [3]=pad
//   [4+o]=S*Wf[o][i]   [14+o]=-S*Wo[o][i]
// ws[480+o] = L*(bo[o]+sum_i Wo[o][i]) ;  S=2*log2e, L=log2e
__global__ void repack_kernel(const float* __restrict__ Wh, const float* __restrict__ bh,
                              const float* __restrict__ Wo, const float* __restrict__ bo,
                              const float* __restrict__ Wf, float* __restrict__ ws) {
    const float S = 2.8853900817779268f;  // 2*log2(e)
    const float L = 1.4426950408889634f;  // log2(e)
    int t = threadIdx.x;
    if (t < HID) {
        float* b = ws + 24 * t;
        b[0] = S * Wh[3 * t + 0];
        b[1] = S * Wh[3 * t + 1];
        b[2] = S * (Wh[3 * t + 2] + bh[t]);
        b[3] = 0.0f;
        for (int o = 0; o < OUT; ++o) {
            b[4 + o]  = S * Wf[o * HID + t];
            b[14 + o] = -S * Wo[o * HID + t];
        }
    } else if (t < HID + OUT) {
        int o = t - HID;
        float s = bo[o];
        for (int i = 0; i < HID; ++i) s += Wo[o * HID + i];
        ws[480 + o] = L * s;
    }
}

// ---- main kernel ----
__global__ __launch_bounds__(256, 8) void pcn_kernel(
    const float* __restrict__ x, const float* __restrict__ prev,
    const float* __restrict__ w, float* __restrict__ out, long B) {
    __shared__ float lds[LDSW];          // 20480 B -> 8 blocks/CU
    const int t = threadIdx.x;
    const long base = (long)blockIdx.x * RPB;
    const int V = (B - base < RPB) ? (int)(B - base) : RPB;
    const int NF = OUT * V;
    const int NF4 = NF >> 2;             // NF%4==0 for B%2==0 tiles (tail loop covers rest)

    // ---- phase 0: stage prev tile AoS-linear into LDS ----
#if __has_builtin(__builtin_amdgcn_global_load_lds)
    {
        const int wv = t >> 6, l = t & 63;
        const float* tsrc = prev + base * OUT;
#pragma unroll
        for (int k = 0; k < 5; ++k) {
            const int g0 = 256 * k + 64 * wv;      // wave's first 16B granule
            const int g = g0 + l;                  // lane granule
            if (g < NF4) {
                __builtin_amdgcn_global_load_lds(
                    (const as1f*)(tsrc + 4 * g),   // per-lane global src
                    (as3f*)(lds + 4 * g0),         // wave-uniform LDS base (+16*lane HW)
                    16, 0, 0);
            }
        }
    }
#else
    {
        const f32x4* src = reinterpret_cast<const f32x4*>(prev + base * OUT);
#pragma unroll
        for (int k = 0; k < 5; ++k) {
            const int idx = t + 256 * k;
            if (idx < NF4) *reinterpret_cast<f32x4*>(lds + 4 * idx) = src[idx];
        }
    }
#endif
    for (int f = (NF4 << 2) + t; f < NF; f += 256) {   // scalar tail (rare)
        lds[f] = prev[base * OUT + f];
    }

    // ---- x loads issued now (consumed after barrier) ----
    const bool aok = t < V;
    const bool bok = (t + 256) < V;
    f32x2 xa = {0.0f, 0.0f}, xb = {0.0f, 0.0f};
    if (aok) xa = *reinterpret_cast<const f32x2*>(x + 2 * (base + t));
    if (bok) xb = *reinterpret_cast<const f32x2*>(x + 2 * (base + t + 256));

    __syncthreads();

    // ---- phase 2: rows from AoS LDS (stride 10 words; 4-way conflict, hidden) ----
    const float* ra = lds + 10 * t;
    const float* rb = lds + 10 * (t + 256);
    const f32x2 x0 = {xa.x, xb.x};
    const f32x2 x1 = {xa.y, xb.y};
#define DECLP(o) f32x2 p##o = {ra[o], rb[o]}; PIN(p##o);
    EACH10(DECLP)
#undef DECLP

    // ---- phase 3: packed f32x2 compute (verified core) ----
#define INITL(o) f32x2 l##o = sp(w[480 + o]);
    EACH10(INITL)
#undef INITL
#pragma unroll
    for (int i = 0; i < HID; ++i) {
        const float* wb = w + 24 * i;
        f32x2 a = sp(wb[2]);
        a += sp(wb[0]) * x0;
        a += sp(wb[1]) * x1;
#define FB(o) a += sp(wb[4 + o]) * p##o;
        EACH10(FB)
#undef FB
        f32x2 r;
        r.x = fast_rcp(1.0f + fast_exp2(a.x));
        r.y = fast_rcp(1.0f + fast_exp2(a.y));
#define LO(o) l##o += sp(wb[14 + o]) * r;
        EACH10(LO)
#undef LO
    }
#define EX(o) l##o.x = fast_exp2(l##o.x); l##o.y = fast_exp2(l##o.y);
    EACH10(EX)
#undef EX
    const f32x2 s = ((l0 + l1) + (l2 + l3)) + (((l4 + l5) + (l6 + l7)) + (l8 + l9));
    f32x2 rs;
    rs.x = fast_rcp(s.x);
    rs.y = fast_rcp(s.y);
#define SC(o) l##o *= rs;
    EACH10(SC)
#undef SC

    // ---- phase 4: results -> same LDS region (dense rows) ----
    __syncthreads();
    if (aok) {
        f32x2* d = reinterpret_cast<f32x2*>(lds + 10 * t);
        d[0] = (f32x2){l0.x, l1.x}; d[1] = (f32x2){l2.x, l3.x};
        d[2] = (f32x2){l4.x, l5.x}; d[3] = (f32x2){l6.x, l7.x};
        d[4] = (f32x2){l8.x, l9.x};
    }
    if (bok) {
        f32x2* d = reinterpret_cast<f32x2*>(lds + 10 * (t + 256));
        d[0] = (f32x2){l0.y, l1.y}; d[1] = (f32x2){l2.y, l3.y};
        d[2] = (f32x2){l4.y, l5.y}; d[3] = (f32x2){l6.y, l7.y};
        d[4] = (f32x2){l8.y, l9.y};
    }
    __syncthreads();

    // ---- phase 5: dense LDS -> global, non-temporal (R8 best) ----
    {
        f32x4* dst = reinterpret_cast<f32x4*>(out + base * OUT);
        const f32x4* sl = reinterpret_cast<const f32x4*>(lds);
#pragma unroll
        for (int k = 0; k < 5; ++k) {
            const int idx = t + 256 * k;
            if (idx < NF4) __builtin_nontemporal_store(sl[idx], dst + idx);
        }
        for (int f = (NF4 << 2) + t; f < NF; f += 256) {
            __builtin_nontemporal_store(lds[f], out + base * OUT + f);
        }
    }
}

// ---- fallback (no workspace): 1 row/thread ----
__global__ __launch_bounds__(256) void pcn_fallback(
    const float* __restrict__ x, const float* __restrict__ prev,
    const float* __restrict__ Wh, const float* __restrict__ bh,
    const float* __restrict__ Wo, const float* __restrict__ bo,
    const float* __restrict__ Wf, float* __restrict__ out, long B) {
    const long r = (long)blockIdx.x * blockDim.x + threadIdx.x;
    if (r >= B) return;
    const float x0 = x[2 * r], x1 = x[2 * r + 1];
#define DECLP(o) float p##o = prev[10 * r + o];
    EACH10(DECLP)
#undef DECLP
#define DECLL(o) float l##o = bo[o];
    EACH10(DECLL)
#undef DECLL
#pragma unroll
    for (int i = 0; i < HID; ++i) {
        float a = fmaf(Wh[3 * i], x0, fmaf(Wh[3 * i + 1], x1, Wh[3 * i + 2] + bh[i]));
#define FB(o) a = fmaf(Wf[o * HID + i], p##o, a);
        EACH10(FB)
#undef FB
        const float h = 1.0f - 2.0f * fast_rcp(1.0f + __expf(2.0f * a));
#define LO(o) l##o = fmaf(Wo[o * HID + i], h, l##o);
        EACH10(LO)
#undef LO
    }
    float m = l0;
#define MX(o) m = fmaxf(m, l##o);
    MX(1) MX(2) MX(3) MX(4) MX(5) MX(6) MX(7) MX(8) MX(9)
#undef MX
    float s = 0.0f;
#define EX(o) l##o = __expf(l##o - m); s += l##o;
    EACH10(EX)
#undef EX
    const float rs = fast_rcp(s);
#define ST(o) out[10 * r + o] = l##o * rs;
    EACH10(ST)
#undef ST
}

extern "C" void kernel_launch(void* const* d_in, const int* in_sizes, int n_in,
                              void* d_out, int out_size, void* d_ws, size_t ws_size,
                              hipStream_t stream) {
    const float* x    = (const float*)d_in[0];
    const float* prev = (const float*)d_in[1];
    const float* Wh   = (const float*)d_in[2];
    const float* bh   = (const float*)d_in[3];
    const float* Wo   = (const float*)d_in[4];
    const float* bo   = (const float*)d_in[5];
    const float* Wf   = (const float*)d_in[6];
    float* out = (float*)d_out;

    const long B = in_sizes[0] / 2;

    if (ws_size >= 490 * sizeof(float)) {
        float* ws = (float*)d_ws;
        repack_kernel<<<1, 64, 0, stream>>>(Wh, bh, Wo, bo, Wf, ws);
        const int grid = (int)((B + RPB - 1) / RPB);
        pcn_kernel<<<grid, 256, 0, stream>>>(x, prev, ws, out, B);
    } else {
        const int gb = (int)((B + 255) / 256);
        pcn_fallback<<<gb, 256, 0, stream>>>(x, prev, Wh, bh, Wo, bo, Wf, out, B);
    }
}